// Round 1
// baseline (247.324 us; speedup 1.0000x reference)
//
#include <hip/hip_runtime.h>
#include <hip/hip_bf16.h>

// ---------------------------------------------------------------------------
// Compile-time computation of the real Wigner-3j tables, mirroring the Python
// reference (_cg, _w3j_complex, _Q, _real_w3j) in double precision.
// PATH_W = sqrt(2*lo+1) is folded into the tables.
// ---------------------------------------------------------------------------

struct Tbl { double v[5][5][5]; };   // max (2l+1)=5 per axis; zero padded
struct CMat { double re[5][5]; double im[5][5]; };

constexpr double cfact(int n) {
    double r = 1.0;
    for (int i = 2; i <= n; ++i) r *= (double)i;
    return r;
}

constexpr double csqrt(double x) {
    if (x <= 0.0) return 0.0;
    double g = x > 1.0 ? x : 1.0;
    for (int i = 0; i < 100; ++i) g = 0.5 * (g + x / g);
    return g;
}

constexpr int cparity(int k) { return (((k % 2) + 2) % 2 == 0) ? 1 : -1; }

constexpr double ccg(int l1, int l2, int l3, int m1, int m2, int m3) {
    if (m1 + m2 != m3) return 0.0;
    double pre = csqrt((2.0 * l3 + 1.0) * cfact(l3 + l1 - l2) * cfact(l3 - l1 + l2) *
                       cfact(l1 + l2 - l3) / cfact(l1 + l2 + l3 + 1));
    pre *= csqrt(cfact(l3 + m3) * cfact(l3 - m3) * cfact(l1 - m1) * cfact(l1 + m1) *
                 cfact(l2 - m2) * cfact(l2 + m2));
    int kmin = 0;
    if (l2 - l3 - m1 > kmin) kmin = l2 - l3 - m1;
    if (l1 - l3 + m2 > kmin) kmin = l1 - l3 + m2;
    int kmax = l1 + l2 - l3;
    if (l1 - m1 < kmax) kmax = l1 - m1;
    if (l2 + m2 < kmax) kmax = l2 + m2;
    double s = 0.0;
    for (int k = kmin; k <= kmax; ++k) {
        s += (double)cparity(k) /
             (cfact(k) * cfact(l1 + l2 - l3 - k) * cfact(l1 - m1 - k) * cfact(l2 + m2 - k) *
              cfact(l3 - l2 + m1 + k) * cfact(l3 - l1 - m2 + k));
    }
    return pre * s;
}

constexpr Tbl cw3j_complex(int l1, int l2, int l3) {
    Tbl w{};
    for (int m1 = -l1; m1 <= l1; ++m1)
        for (int m2 = -l2; m2 <= l2; ++m2) {
            int m3 = -(m1 + m2);
            if (m3 >= -l3 && m3 <= l3) {
                w.v[m1 + l1][m2 + l2][m3 + l3] =
                    (double)cparity(l1 - l2 - m3) * ccg(l1, l2, l3, m1, m2, m1 + m2) /
                    csqrt(2.0 * l3 + 1.0);
            }
        }
    return w;
}

constexpr CMat cQ(int l) {
    CMat q{};
    q.re[l][l] = 1.0;
    double s2 = csqrt(2.0);
    for (int m = 1; m <= l; ++m) {
        q.re[l + m][l + m] = (double)cparity(m) / s2;
        q.re[l + m][l - m] = 1.0 / s2;
        q.im[l - m][l - m] = 1.0 / s2;
        q.im[l - m][l + m] = -(double)cparity(m) / s2;
    }
    return q;
}

constexpr Tbl creal_w3j(int l1, int l2, int l3) {
    const CMat q1 = cQ(l1), q2 = cQ(l2), q3 = cQ(l3);
    const Tbl w = cw3j_complex(l1, l2, l3);
    const int n1 = 2 * l1 + 1, n2 = 2 * l2 + 1, n3 = 2 * l3 + 1;
    // t1[A][B][c] = sum_C w[A][B][C] * q3[c][C]   (w real, q3 complex)
    Tbl t1re{}, t1im{};
    for (int A = 0; A < n1; ++A)
        for (int B = 0; B < n2; ++B)
            for (int c = 0; c < n3; ++c) {
                double re = 0.0, im = 0.0;
                for (int C = 0; C < n3; ++C) {
                    re += w.v[A][B][C] * q3.re[c][C];
                    im += w.v[A][B][C] * q3.im[c][C];
                }
                t1re.v[A][B][c] = re;
                t1im.v[A][B][c] = im;
            }
    // t2[A][b][c] = sum_B q2[b][B] * t1[A][B][c]
    Tbl t2re{}, t2im{};
    for (int A = 0; A < n1; ++A)
        for (int b = 0; b < n2; ++b)
            for (int c = 0; c < n3; ++c) {
                double re = 0.0, im = 0.0;
                for (int B = 0; B < n2; ++B) {
                    re += q2.re[b][B] * t1re.v[A][B][c] - q2.im[b][B] * t1im.v[A][B][c];
                    im += q2.re[b][B] * t1im.v[A][B][c] + q2.im[b][B] * t1re.v[A][B][c];
                }
                t2re.v[A][b][c] = re;
                t2im.v[A][b][c] = im;
            }
    // T[a][b][c] = sum_A q1[a][A] * t2[A][b][c]
    Tbl Tre{}, Tim{};
    for (int a = 0; a < n1; ++a)
        for (int b = 0; b < n2; ++b)
            for (int c = 0; c < n3; ++c) {
                double re = 0.0, im = 0.0;
                for (int A = 0; A < n1; ++A) {
                    re += q1.re[a][A] * t2re.v[A][b][c] - q1.im[a][A] * t2im.v[A][b][c];
                    im += q1.re[a][A] * t2im.v[A][b][c] + q1.im[a][A] * t2re.v[A][b][c];
                }
                Tre.v[a][b][c] = re;
                Tim.v[a][b][c] = im;
            }
    // pick re or im by Frobenius norm, normalize, fold PATH_W = sqrt(2*l3+1)
    double nre = 0.0, nim = 0.0;
    for (int a = 0; a < n1; ++a)
        for (int b = 0; b < n2; ++b)
            for (int c = 0; c < n3; ++c) {
                nre += Tre.v[a][b][c] * Tre.v[a][b][c];
                nim += Tim.v[a][b][c] * Tim.v[a][b][c];
            }
    const bool useRe = (nre >= nim);
    const double norm = csqrt(useRe ? nre : nim);
    const double scale = csqrt(2.0 * l3 + 1.0) / norm;
    Tbl out{};
    for (int a = 0; a < n1; ++a)
        for (int b = 0; b < n2; ++b)
            for (int c = 0; c < n3; ++c) {
                // emulate .astype(float32) of the normalized table, then * PATH_W
                float t32 = (float)((useRe ? Tre.v[a][b][c] : Tim.v[a][b][c]) / norm);
                out.v[a][b][c] = (double)t32 * csqrt(2.0 * l3 + 1.0);
                (void)scale;
            }
    return out;
}

// INSTR = [(0,0,0),(0,1,1),(0,2,2),(1,0,1),(1,1,0),(1,1,1),(1,1,2),(1,2,1),
//          (1,2,2),(2,0,2),(2,1,1),(2,1,2),(2,2,0),(2,2,1),(2,2,2)]
constexpr Tbl CG[15] = {
    creal_w3j(0, 0, 0), creal_w3j(0, 1, 1), creal_w3j(0, 2, 2), creal_w3j(1, 0, 1),
    creal_w3j(1, 1, 0), creal_w3j(1, 1, 1), creal_w3j(1, 1, 2), creal_w3j(1, 2, 1),
    creal_w3j(1, 2, 2), creal_w3j(2, 0, 2), creal_w3j(2, 1, 1), creal_w3j(2, 1, 2),
    creal_w3j(2, 2, 0), creal_w3j(2, 2, 1), creal_w3j(2, 2, 2)};

// ---------------------------------------------------------------------------
// Kernel: one wave (64 lanes) per element; lane = mul channel u.
// All CG loops fully unrolled; zero coefficients fold away at compile time.
// ---------------------------------------------------------------------------

#define MUL_C 64
#define DIM1_C 576
#define DIM2_C 9
#define WDIM_C 960
#define ODIM_C 3264

template <int IDX, int N1, int N2, int N3>
__device__ __forceinline__ void do_path(const float (&a)[N1], const float (&b)[N2], float w,
                                        float* __restrict__ op) {
    float t[N3];
#pragma unroll
    for (int k = 0; k < N3; ++k) t[k] = 0.0f;
#pragma unroll
    for (int i = 0; i < N1; ++i) {
#pragma unroll
        for (int j = 0; j < N2; ++j) {
            const float p = a[i] * b[j];
#pragma unroll
            for (int k = 0; k < N3; ++k) {
                constexpr const Tbl& T = CG[IDX];
                const float c = (float)T.v[i][j][k];
                if (c != 0.0f) t[k] = fmaf(c, p, t[k]);
            }
        }
    }
#pragma unroll
    for (int k = 0; k < N3; ++k) op[k] = t[k] * w;
}

__global__ __launch_bounds__(256) void tp_kernel(const float* __restrict__ x1,
                                                 const float* __restrict__ x2,
                                                 const float* __restrict__ wgt,
                                                 float* __restrict__ out, int n) {
    const int tid = blockIdx.x * blockDim.x + threadIdx.x;
    const int e = tid >> 6;   // one wave per element
    const int u = tid & 63;   // lane = mul channel
    if (e >= n) return;

    const float* __restrict__ x1e = x1 + (size_t)e * DIM1_C;
    const float* __restrict__ x2e = x2 + (size_t)e * DIM2_C;
    const float* __restrict__ we = wgt + (size_t)e * WDIM_C;
    float* __restrict__ oe = out + (size_t)e * ODIM_C;

    // x1 slices for this channel: l=0 (1), l=1 (3), l=2 (5)
    float a0[1], a1[3], a2[5];
    a0[0] = x1e[u];
#pragma unroll
    for (int i = 0; i < 3; ++i) a1[i] = x1e[64 + u * 3 + i];
#pragma unroll
    for (int i = 0; i < 5; ++i) a2[i] = x1e[256 + u * 5 + i];

    // x2 slices (uniform across the wave)
    float b0[1], b1[3], b2[5];
    b0[0] = x2e[0];
#pragma unroll
    for (int j = 0; j < 3; ++j) b1[j] = x2e[1 + j];
#pragma unroll
    for (int j = 0; j < 5; ++j) b2[j] = x2e[4 + j];

    // 15 paths; output offsets are cumulative MUL*(2lo+1)
    do_path<0, 1, 1, 1>(a0, b0, we[0 * 64 + u], oe + 0 + u * 1);
    do_path<1, 1, 3, 3>(a0, b1, we[1 * 64 + u], oe + 64 + u * 3);
    do_path<2, 1, 5, 5>(a0, b2, we[2 * 64 + u], oe + 256 + u * 5);
    do_path<3, 3, 1, 3>(a1, b0, we[3 * 64 + u], oe + 576 + u * 3);
    do_path<4, 3, 3, 1>(a1, b1, we[4 * 64 + u], oe + 768 + u * 1);
    do_path<5, 3, 3, 3>(a1, b1, we[5 * 64 + u], oe + 832 + u * 3);
    do_path<6, 3, 3, 5>(a1, b1, we[6 * 64 + u], oe + 1024 + u * 5);
    do_path<7, 3, 5, 3>(a1, b2, we[7 * 64 + u], oe + 1344 + u * 3);
    do_path<8, 3, 5, 5>(a1, b2, we[8 * 64 + u], oe + 1536 + u * 5);
    do_path<9, 5, 1, 5>(a2, b0, we[9 * 64 + u], oe + 1856 + u * 5);
    do_path<10, 5, 3, 3>(a2, b1, we[10 * 64 + u], oe + 2176 + u * 3);
    do_path<11, 5, 3, 5>(a2, b1, we[11 * 64 + u], oe + 2368 + u * 5);
    do_path<12, 5, 5, 1>(a2, b2, we[12 * 64 + u], oe + 2688 + u * 1);
    do_path<13, 5, 5, 3>(a2, b2, we[13 * 64 + u], oe + 2752 + u * 3);
    do_path<14, 5, 5, 5>(a2, b2, we[14 * 64 + u], oe + 2944 + u * 5);
}

extern "C" void kernel_launch(void* const* d_in, const int* in_sizes, int n_in, void* d_out,
                              int out_size, void* d_ws, size_t ws_size, hipStream_t stream) {
    const float* x1 = (const float*)d_in[0];
    const float* x2 = (const float*)d_in[1];
    const float* w = (const float*)d_in[2];
    float* out = (float*)d_out;
    const int n = in_sizes[0] / DIM1_C;  // E
    const int threads = n * 64;
    const int block = 256;
    const int grid = (threads + block - 1) / block;
    tp_kernel<<<grid, block, 0, stream>>>(x1, x2, w, out, n);
}

// Round 2
// 235.077 us; speedup vs baseline: 1.0521x; 1.0521x over previous
//
#include <hip/hip_runtime.h>
#include <hip/hip_bf16.h>

// ---------------------------------------------------------------------------
// Compile-time computation of the real Wigner-3j tables, mirroring the Python
// reference (_cg, _w3j_complex, _Q, _real_w3j) in double precision.
// PATH_W = sqrt(2*lo+1) is folded into the tables.
// ---------------------------------------------------------------------------

struct Tbl { double v[5][5][5]; };   // max (2l+1)=5 per axis; zero padded
struct CMat { double re[5][5]; double im[5][5]; };

constexpr double cfact(int n) {
    double r = 1.0;
    for (int i = 2; i <= n; ++i) r *= (double)i;
    return r;
}

constexpr double csqrt(double x) {
    if (x <= 0.0) return 0.0;
    double g = x > 1.0 ? x : 1.0;
    for (int i = 0; i < 100; ++i) g = 0.5 * (g + x / g);
    return g;
}

constexpr int cparity(int k) { return (((k % 2) + 2) % 2 == 0) ? 1 : -1; }

constexpr double ccg(int l1, int l2, int l3, int m1, int m2, int m3) {
    if (m1 + m2 != m3) return 0.0;
    double pre = csqrt((2.0 * l3 + 1.0) * cfact(l3 + l1 - l2) * cfact(l3 - l1 + l2) *
                       cfact(l1 + l2 - l3) / cfact(l1 + l2 + l3 + 1));
    pre *= csqrt(cfact(l3 + m3) * cfact(l3 - m3) * cfact(l1 - m1) * cfact(l1 + m1) *
                 cfact(l2 - m2) * cfact(l2 + m2));
    int kmin = 0;
    if (l2 - l3 - m1 > kmin) kmin = l2 - l3 - m1;
    if (l1 - l3 + m2 > kmin) kmin = l1 - l3 + m2;
    int kmax = l1 + l2 - l3;
    if (l1 - m1 < kmax) kmax = l1 - m1;
    if (l2 + m2 < kmax) kmax = l2 + m2;
    double s = 0.0;
    for (int k = kmin; k <= kmax; ++k) {
        s += (double)cparity(k) /
             (cfact(k) * cfact(l1 + l2 - l3 - k) * cfact(l1 - m1 - k) * cfact(l2 + m2 - k) *
              cfact(l3 - l2 + m1 + k) * cfact(l3 - l1 - m2 + k));
    }
    return pre * s;
}

constexpr Tbl cw3j_complex(int l1, int l2, int l3) {
    Tbl w{};
    for (int m1 = -l1; m1 <= l1; ++m1)
        for (int m2 = -l2; m2 <= l2; ++m2) {
            int m3 = -(m1 + m2);
            if (m3 >= -l3 && m3 <= l3) {
                w.v[m1 + l1][m2 + l2][m3 + l3] =
                    (double)cparity(l1 - l2 - m3) * ccg(l1, l2, l3, m1, m2, m1 + m2) /
                    csqrt(2.0 * l3 + 1.0);
            }
        }
    return w;
}

constexpr CMat cQ(int l) {
    CMat q{};
    q.re[l][l] = 1.0;
    double s2 = csqrt(2.0);
    for (int m = 1; m <= l; ++m) {
        q.re[l + m][l + m] = (double)cparity(m) / s2;
        q.re[l + m][l - m] = 1.0 / s2;
        q.im[l - m][l - m] = 1.0 / s2;
        q.im[l - m][l + m] = -(double)cparity(m) / s2;
    }
    return q;
}

constexpr Tbl creal_w3j(int l1, int l2, int l3) {
    const CMat q1 = cQ(l1), q2 = cQ(l2), q3 = cQ(l3);
    const Tbl w = cw3j_complex(l1, l2, l3);
    const int n1 = 2 * l1 + 1, n2 = 2 * l2 + 1, n3 = 2 * l3 + 1;
    Tbl t1re{}, t1im{};
    for (int A = 0; A < n1; ++A)
        for (int B = 0; B < n2; ++B)
            for (int c = 0; c < n3; ++c) {
                double re = 0.0, im = 0.0;
                for (int C = 0; C < n3; ++C) {
                    re += w.v[A][B][C] * q3.re[c][C];
                    im += w.v[A][B][C] * q3.im[c][C];
                }
                t1re.v[A][B][c] = re;
                t1im.v[A][B][c] = im;
            }
    Tbl t2re{}, t2im{};
    for (int A = 0; A < n1; ++A)
        for (int b = 0; b < n2; ++b)
            for (int c = 0; c < n3; ++c) {
                double re = 0.0, im = 0.0;
                for (int B = 0; B < n2; ++B) {
                    re += q2.re[b][B] * t1re.v[A][B][c] - q2.im[b][B] * t1im.v[A][B][c];
                    im += q2.re[b][B] * t1im.v[A][B][c] + q2.im[b][B] * t1re.v[A][B][c];
                }
                t2re.v[A][b][c] = re;
                t2im.v[A][b][c] = im;
            }
    Tbl Tre{}, Tim{};
    for (int a = 0; a < n1; ++a)
        for (int b = 0; b < n2; ++b)
            for (int c = 0; c < n3; ++c) {
                double re = 0.0, im = 0.0;
                for (int A = 0; A < n1; ++A) {
                    re += q1.re[a][A] * t2re.v[A][b][c] - q1.im[a][A] * t2im.v[A][b][c];
                    im += q1.re[a][A] * t2im.v[A][b][c] + q1.im[a][A] * t2re.v[A][b][c];
                }
                Tre.v[a][b][c] = re;
                Tim.v[a][b][c] = im;
            }
    double nre = 0.0, nim = 0.0;
    for (int a = 0; a < n1; ++a)
        for (int b = 0; b < n2; ++b)
            for (int c = 0; c < n3; ++c) {
                nre += Tre.v[a][b][c] * Tre.v[a][b][c];
                nim += Tim.v[a][b][c] * Tim.v[a][b][c];
            }
    const bool useRe = (nre >= nim);
    const double norm = csqrt(useRe ? nre : nim);
    Tbl out{};
    for (int a = 0; a < n1; ++a)
        for (int b = 0; b < n2; ++b)
            for (int c = 0; c < n3; ++c) {
                float t32 = (float)((useRe ? Tre.v[a][b][c] : Tim.v[a][b][c]) / norm);
                out.v[a][b][c] = (double)t32 * csqrt(2.0 * l3 + 1.0);
            }
    return out;
}

constexpr Tbl CG[15] = {
    creal_w3j(0, 0, 0), creal_w3j(0, 1, 1), creal_w3j(0, 2, 2), creal_w3j(1, 0, 1),
    creal_w3j(1, 1, 0), creal_w3j(1, 1, 1), creal_w3j(1, 1, 2), creal_w3j(1, 2, 1),
    creal_w3j(1, 2, 2), creal_w3j(2, 0, 2), creal_w3j(2, 1, 1), creal_w3j(2, 1, 2),
    creal_w3j(2, 2, 0), creal_w3j(2, 2, 1), creal_w3j(2, 2, 2)};

// ---------------------------------------------------------------------------
// Kernel: 4 waves per block, one element per wave; lane = mul channel u.
// Compute results go to an LDS staging tile; the block then streams the
// contiguous 4x3264-float region to global as pure float4 stores.
// ---------------------------------------------------------------------------

#define MUL_C 64
#define DIM1_C 576
#define DIM2_C 9
#define WDIM_C 960
#define ODIM_C 3264
#define EPB 4  // elements (waves) per block

template <int IDX, int N1, int N2, int N3>
__device__ __forceinline__ void do_path(const float (&a)[N1], const float (&b)[N2], float w,
                                        float* op) {
    float t[N3];
#pragma unroll
    for (int k = 0; k < N3; ++k) t[k] = 0.0f;
#pragma unroll
    for (int i = 0; i < N1; ++i) {
#pragma unroll
        for (int j = 0; j < N2; ++j) {
            const float p = a[i] * b[j];
#pragma unroll
            for (int k = 0; k < N3; ++k) {
                constexpr const Tbl& T = CG[IDX];
                const float c = (float)T.v[i][j][k];
                if (c != 0.0f) t[k] = fmaf(c, p, t[k]);
            }
        }
    }
#pragma unroll
    for (int k = 0; k < N3; ++k) op[k] = t[k] * w;
}

__global__ __launch_bounds__(256) void tp_kernel(const float* __restrict__ x1,
                                                 const float* __restrict__ x2,
                                                 const float* __restrict__ wgt,
                                                 float* __restrict__ out, int n) {
    __shared__ float sout[EPB * ODIM_C];  // 52,224 B

    const int wv = threadIdx.x >> 6;  // wave in block
    const int u = threadIdx.x & 63;   // lane = mul channel
    const int e = blockIdx.x * EPB + wv;

    if (e < n) {
        const float* __restrict__ x1e = x1 + (size_t)e * DIM1_C;
        const float* __restrict__ x2e = x2 + (size_t)e * DIM2_C;
        const float* __restrict__ we = wgt + (size_t)e * WDIM_C;
        float* oe = &sout[wv * ODIM_C];

        float a0[1], a1[3], a2[5];
        a0[0] = x1e[u];
#pragma unroll
        for (int i = 0; i < 3; ++i) a1[i] = x1e[64 + u * 3 + i];
#pragma unroll
        for (int i = 0; i < 5; ++i) a2[i] = x1e[256 + u * 5 + i];

        float b0[1], b1[3], b2[5];
        b0[0] = x2e[0];
#pragma unroll
        for (int j = 0; j < 3; ++j) b1[j] = x2e[1 + j];
#pragma unroll
        for (int j = 0; j < 5; ++j) b2[j] = x2e[4 + j];

        do_path<0, 1, 1, 1>(a0, b0, we[0 * 64 + u], oe + 0 + u * 1);
        do_path<1, 1, 3, 3>(a0, b1, we[1 * 64 + u], oe + 64 + u * 3);
        do_path<2, 1, 5, 5>(a0, b2, we[2 * 64 + u], oe + 256 + u * 5);
        do_path<3, 3, 1, 3>(a1, b0, we[3 * 64 + u], oe + 576 + u * 3);
        do_path<4, 3, 3, 1>(a1, b1, we[4 * 64 + u], oe + 768 + u * 1);
        do_path<5, 3, 3, 3>(a1, b1, we[5 * 64 + u], oe + 832 + u * 3);
        do_path<6, 3, 3, 5>(a1, b1, we[6 * 64 + u], oe + 1024 + u * 5);
        do_path<7, 3, 5, 3>(a1, b2, we[7 * 64 + u], oe + 1344 + u * 3);
        do_path<8, 3, 5, 5>(a1, b2, we[8 * 64 + u], oe + 1536 + u * 5);
        do_path<9, 5, 1, 5>(a2, b0, we[9 * 64 + u], oe + 1856 + u * 5);
        do_path<10, 5, 3, 3>(a2, b1, we[10 * 64 + u], oe + 2176 + u * 3);
        do_path<11, 5, 3, 5>(a2, b1, we[11 * 64 + u], oe + 2368 + u * 5);
        do_path<12, 5, 5, 1>(a2, b2, we[12 * 64 + u], oe + 2688 + u * 1);
        do_path<13, 5, 5, 3>(a2, b2, we[13 * 64 + u], oe + 2752 + u * 3);
        do_path<14, 5, 5, 5>(a2, b2, we[14 * 64 + u], oe + 2944 + u * 5);
    }

    __syncthreads();

    // Cooperative float4 streaming store of the block's contiguous output tile.
    const int base_e = blockIdx.x * EPB;
    int nvalid = n - base_e;
    if (nvalid > EPB) nvalid = EPB;
    if (nvalid <= 0) return;
    const int total4 = nvalid * (ODIM_C / 4);  // float4 count
    float4* __restrict__ outv = (float4*)(out + (size_t)base_e * ODIM_C);
    const float4* sv = (const float4*)&sout[0];
    for (int i = threadIdx.x; i < total4; i += 256) {
        outv[i] = sv[i];
    }
}

extern "C" void kernel_launch(void* const* d_in, const int* in_sizes, int n_in, void* d_out,
                              int out_size, void* d_ws, size_t ws_size, hipStream_t stream) {
    const float* x1 = (const float*)d_in[0];
    const float* x2 = (const float*)d_in[1];
    const float* w = (const float*)d_in[2];
    float* out = (float*)d_out;
    const int n = in_sizes[0] / DIM1_C;  // E
    const int grid = (n + EPB - 1) / EPB;
    tp_kernel<<<grid, 256, 0, stream>>>(x1, x2, w, out, n);
}